// Round 2
// baseline (268.400 us; speedup 1.0000x reference)
//
#include <hip/hip_runtime.h>
#include <stdint.h>

// Problem dims (VectorNet): B=64, NA=49, NM=19, P=128, IN=64, H=64, OUT=60, H2=128
#define B_    64
#define NA_   49
#define NM_   19
#define P_    128
#define OUT_  60
#define XST   132   // padded row stride (floats) for activation tiles in LDS

// ---------------------------------------------------------------------------
// SubNetwork: 3x (Linear(K->64) + LayerNorm + ReLU -> concat(h, neighbor_max))
// One block handles GPB graphs of NODES nodes. All activations live in LDS.
// Final layer: poly = max over nodes of concat(h, nmax) == [max h, max h].
// out_feats layout: [node_slot][B][128] fp32; slot = out_offset + graph_idx.
// ---------------------------------------------------------------------------
template<int NODES, int GPB>
__global__ __launch_bounds__(256, 2) void subnet_kernel(
    const float* __restrict__ in_feat,  // [NG][NODES][64] fp32
    const float* __restrict__ w0, const float* __restrict__ b0,
    const float* __restrict__ g0, const float* __restrict__ n0,
    const float* __restrict__ w1, const float* __restrict__ b1,
    const float* __restrict__ g1, const float* __restrict__ n1,
    const float* __restrict__ w2, const float* __restrict__ b2,
    const float* __restrict__ g2, const float* __restrict__ n2,
    float* __restrict__ out_feats, int out_offset)
{
  constexpr int ROWS = NODES * GPB;        // total node-rows in this block
  constexpr int R    = (ROWS + 15) / 16;   // rows per mm-group (max)

  __shared__ __align__(16) float Ws[128 * 64];           // [k][c] (32 KB)
  __shared__ __align__(16) float Xs[GPB][NODES * XST];   // activations, padded
  __shared__ float Bs[64], Gs[64], Ns[64]; // bias / gamma / beta

  const int tid = threadIdx.x;
  const int cc  = tid & 15;       // c-group: 4 consecutive channels
  const int mm  = tid >> 4;       // row-group
  const int c4  = cc * 4;
  const int gbase = blockIdx.x * GPB;

  // balanced row assignment: row ri = mm + 16*r, ri < ROWS; (g, m) = divmod
  int gi[R], mi[R]; bool valid[R];
#pragma unroll
  for (int r = 0; r < R; ++r) {
    int ri = mm + 16 * r;
    valid[r] = (ri < ROWS);
    int rc = valid[r] ? ri : 0;
    gi[r] = rc / NODES;
    mi[r] = rc % NODES;
  }

  // stage input features (layer 0 uses only k<64), float4-vectorized
  for (int i = tid; i < GPB * NODES * 16; i += 256) {
    int g = i / (NODES * 16);
    int rem = i - g * (NODES * 16);
    int n = rem >> 4, k4 = (rem & 15) * 4;
    float4 v = *(const float4*)&in_feat[((size_t)(gbase + g) * NODES + n) * 64 + k4];
    *(float4*)&Xs[g][n * XST + k4] = v;
  }

  const float* Wp[3] = { w0, w1, w2 };
  const float* Bp[3] = { b0, b1, b2 };
  const float* Gp[3] = { g0, g1, g2 };
  const float* Np[3] = { n0, n1, n2 };

  for (int layer = 0; layer < 3; ++layer) {
    const int K = (layer == 0) ? 64 : 128;

    // stage weights + norm params for this layer
    for (int i = tid; i < K * 16; i += 256)
      ((float4*)Ws)[i] = ((const float4*)Wp[layer])[i];
    if (tid < 64) {
      Bs[tid] = Bp[layer][tid];
      Gs[tid] = Gp[layer][tid];
      Ns[tid] = Np[layer][tid];
    }
    __syncthreads();

    // matmul: acc[r][j] = sum_k Xs[g][m][k] * Ws[k][c4+j]
    float acc[R][4];
#pragma unroll
    for (int r = 0; r < R; ++r)
      acc[r][0] = acc[r][1] = acc[r][2] = acc[r][3] = 0.f;

    for (int k = 0; k < K; k += 4) {
      float4 wv0 = *(const float4*)&Ws[(k + 0) * 64 + c4];
      float4 wv1 = *(const float4*)&Ws[(k + 1) * 64 + c4];
      float4 wv2 = *(const float4*)&Ws[(k + 2) * 64 + c4];
      float4 wv3 = *(const float4*)&Ws[(k + 3) * 64 + c4];
#pragma unroll
      for (int r = 0; r < R; ++r) {
        if (valid[r]) {
          float4 xv = *(const float4*)&Xs[gi[r]][mi[r] * XST + k];
          acc[r][0] += xv.x * wv0.x + xv.y * wv1.x + xv.z * wv2.x + xv.w * wv3.x;
          acc[r][1] += xv.x * wv0.y + xv.y * wv1.y + xv.z * wv2.y + xv.w * wv3.y;
          acc[r][2] += xv.x * wv0.z + xv.y * wv1.z + xv.z * wv2.z + xv.w * wv3.z;
          acc[r][3] += xv.x * wv0.w + xv.y * wv1.w + xv.z * wv2.w + xv.w * wv3.w;
        }
      }
    }

    // bias + LayerNorm(64) + ReLU, stats via 16-lane shfl reduce
    float hreg[R][4];
#pragma unroll
    for (int r = 0; r < R; ++r) {
      float v0 = acc[r][0] + Bs[c4 + 0];
      float v1 = acc[r][1] + Bs[c4 + 1];
      float v2 = acc[r][2] + Bs[c4 + 2];
      float v3 = acc[r][3] + Bs[c4 + 3];
      float s = v0 + v1 + v2 + v3;
      float q = v0 * v0 + v1 * v1 + v2 * v2 + v3 * v3;
#pragma unroll
      for (int off = 1; off < 16; off <<= 1) {
        s += __shfl_xor(s, off);
        q += __shfl_xor(q, off);
      }
      float mu   = s * 0.015625f;             // /64
      float var  = q * 0.015625f - mu * mu;
      float rstd = rsqrtf(var + 1e-5f);
      hreg[r][0] = fmaxf(0.f, Gs[c4 + 0] * (v0 - mu) * rstd + Ns[c4 + 0]);
      hreg[r][1] = fmaxf(0.f, Gs[c4 + 1] * (v1 - mu) * rstd + Ns[c4 + 1]);
      hreg[r][2] = fmaxf(0.f, Gs[c4 + 2] * (v2 - mu) * rstd + Ns[c4 + 2]);
      hreg[r][3] = fmaxf(0.f, Gs[c4 + 3] * (v3 - mu) * rstd + Ns[c4 + 3]);
    }
    __syncthreads();  // all matmul reads of Xs done before overwriting

#pragma unroll
    for (int r = 0; r < R; ++r) {
      if (valid[r]) {
        *(float4*)&Xs[gi[r]][mi[r] * XST + c4] =
            make_float4(hreg[r][0], hreg[r][1], hreg[r][2], hreg[r][3]);
      }
    }
    __syncthreads();

    if (layer < 2) {
      // neighbor-max via top-2 per (g, channel), write to upper half [64..127]
      if (tid < GPB * 64) {
        int g = tid >> 6;
        int c = tid & 63;
        float m1 = -3.4e38f, m2 = -3.4e38f;
        for (int n = 0; n < NODES; ++n) {
          float v = Xs[g][n * XST + c];
          if (v > m1) { m2 = m1; m1 = v; } else m2 = fmaxf(m2, v);
        }
        for (int n = 0; n < NODES; ++n) {
          float v = Xs[g][n * XST + c];
          Xs[g][n * XST + 64 + c] = (v == m1) ? m2 : m1;
        }
      }
      __syncthreads();
    } else {
      // poly = max over nodes; both halves equal max_n h  (N >= 2)
      if (tid < GPB * 64) {
        int g = tid >> 6;
        int c = tid & 63;
        float m1 = -3.4e38f;
        for (int n = 0; n < NODES; ++n) m1 = fmaxf(m1, Xs[g][n * XST + c]);
        size_t slot = (size_t)(out_offset + gbase + g);
        out_feats[slot * 128 + c]      = m1;
        out_feats[slot * 128 + 64 + c] = m1;
      }
    }
  }
}

// ---------------------------------------------------------------------------
// GAT (only destination node 0 is read) + readout MLP. One block per batch b.
//   wa_src = W @ a_src ; wa_dst = W @ a_dst            (128 each)
//   s_i = feats_i . wa_src ; d0 = feats_0 . wa_dst
//   alpha = softmax_{i=1..128}( leaky(s_i + d0) )
//   u = sum_i alpha_i feats_i ; hg0 = u @ W ; out = hg0 @ mlp_w + mlp_b
// ---------------------------------------------------------------------------
__global__ __launch_bounds__(256) void gat_kernel(
    const float* __restrict__ feats,    // [129][B][128] fp32
    const float* __restrict__ fcw,      // [128][128]
    const float* __restrict__ attnw,    // [256]
    const float* __restrict__ mlpw,     // [128][60]
    const float* __restrict__ mlpb,     // [60]
    float* __restrict__ out)            // [B][60]
{
  const int b = blockIdx.x, tid = threadIdx.x;
  __shared__ float asrc[128], adst[128], was[128], wad[128];
  __shared__ float si[130];             // si[0..128]; si[129] = d0
  __shared__ float alpha[128], red[8], ubuf[128], hg[128];

  if (tid < 128) { asrc[tid] = attnw[tid]; adst[tid] = attnw[128 + tid]; }
  __syncthreads();

  if (tid < 128) {
    float s1 = 0.f, s2 = 0.f;
    for (int c = 0; c < 128; ++c) {
      float w = fcw[tid * 128 + c];
      s1 += w * asrc[c];
      s2 += w * adst[c];
    }
    was[tid] = s1; wad[tid] = s2;
  }
  __syncthreads();

  if (tid < 130) {
    const float* wa = (tid == 129) ? wad : was;
    int node = (tid == 129) ? 0 : tid;
    const float* fr = feats + ((size_t)node * B_ + b) * 128;
    float s = 0.f;
    for (int k = 0; k < 128; k += 4) {
      float4 f = *(const float4*)&fr[k];
      s += f.x * wa[k] + f.y * wa[k + 1] + f.z * wa[k + 2] + f.w * wa[k + 3];
    }
    si[tid] = s;
  }
  __syncthreads();

  float d0 = si[129];
  float e = -3.4e38f;
  if (tid < 128) {
    float x = si[tid + 1] + d0;
    e = (x > 0.f) ? x : 0.01f * x;    // leaky_relu 0.01
  }
  float m = e;
#pragma unroll
  for (int off = 32; off; off >>= 1) m = fmaxf(m, __shfl_xor(m, off));
  if ((tid & 63) == 0) red[tid >> 6] = m;
  __syncthreads();
  float mx = fmaxf(red[0], red[1]);
  float p = (tid < 128) ? expf(e - mx) : 0.f;
  float s = p;
#pragma unroll
  for (int off = 32; off; off >>= 1) s += __shfl_xor(s, off);
  if ((tid & 63) == 0) red[4 + (tid >> 6)] = s;
  __syncthreads();
  float denom = red[4] + red[5];
  if (tid < 128) alpha[tid] = p / denom;
  __syncthreads();

  if (tid < 128) {
    float u = 0.f;
    for (int t = 0; t < 128; ++t)
      u += alpha[t] * feats[((size_t)(t + 1) * B_ + b) * 128 + tid];
    ubuf[tid] = u;
  }
  __syncthreads();

  if (tid < 128) {
    float hh = 0.f;
    for (int k = 0; k < 128; ++k) hh += ubuf[k] * fcw[k * 128 + tid];
    hg[tid] = hh;
  }
  __syncthreads();

  if (tid < OUT_) {
    float o = mlpb[tid];
    for (int c = 0; c < 128; ++c) o += hg[c] * mlpw[c * OUT_ + tid];
    out[b * OUT_ + tid] = o;
  }
}

// ---------------------------------------------------------------------------
extern "C" void kernel_launch(void* const* d_in, const int* in_sizes, int n_in,
                              void* d_out, int out_size, void* d_ws, size_t ws_size,
                              hipStream_t stream) {
  (void)in_sizes; (void)n_in; (void)out_size; (void)ws_size;

  const float* agent = (const float*)d_in[0];   // [B][NA][64]
  const float* mapf  = (const float*)d_in[1];   // [P][B][NM][64]
  // d_in[2] = map_mask (all ones, unused)

  const float* aw0 = (const float*)d_in[3];
  const float* ab0 = (const float*)d_in[4];
  const float* ag0 = (const float*)d_in[5];
  const float* an0 = (const float*)d_in[6];
  const float* aw1 = (const float*)d_in[7];
  const float* ab1 = (const float*)d_in[8];
  const float* ag1 = (const float*)d_in[9];
  const float* an1 = (const float*)d_in[10];
  const float* aw2 = (const float*)d_in[11];
  const float* ab2 = (const float*)d_in[12];
  const float* ag2 = (const float*)d_in[13];
  const float* an2 = (const float*)d_in[14];

  const float* mw0 = (const float*)d_in[15];
  const float* mb0 = (const float*)d_in[16];
  const float* mg0 = (const float*)d_in[17];
  const float* mn0 = (const float*)d_in[18];
  const float* mw1 = (const float*)d_in[19];
  const float* mb1 = (const float*)d_in[20];
  const float* mg1 = (const float*)d_in[21];
  const float* mn1 = (const float*)d_in[22];
  const float* mw2 = (const float*)d_in[23];
  const float* mb2 = (const float*)d_in[24];
  const float* mg2 = (const float*)d_in[25];
  const float* mn2 = (const float*)d_in[26];

  const float* fcw   = (const float*)d_in[27];
  const float* attnw = (const float*)d_in[28];
  const float* mlpw  = (const float*)d_in[29];
  const float* mlpb  = (const float*)d_in[30];

  float* feats = (float*)d_ws;                 // [129][B][128] fp32 = 4.2 MB
  float* out = (float*)d_out;

  // map subnet: 8192 graphs, 2 per block; poly -> slots [B .. B+8191]
  subnet_kernel<NM_, 2><<<(P_ * B_) / 2, 256, 0, stream>>>(
      mapf, mw0, mb0, mg0, mn0, mw1, mb1, mg1, mn1, mw2, mb2, mg2, mn2,
      feats, B_);

  // agent subnet: 64 graphs, 1 per block; poly -> slots [0 .. B-1]
  subnet_kernel<NA_, 1><<<B_, 256, 0, stream>>>(
      agent, aw0, ab0, ag0, an0, aw1, ab1, ag1, an1, aw2, ab2, ag2, an2,
      feats, 0);

  // GAT column-0 + MLP readout
  gat_kernel<<<B_, 256, 0, stream>>>(feats, fcw, attnw, mlpw, mlpb, out);
}

// Round 3
// 113.373 us; speedup vs baseline: 2.3674x; 2.3674x over previous
//
#include <hip/hip_runtime.h>
#include <stdint.h>

// Problem dims (VectorNet): B=64, NA=49, NM=19, P=128, IN=64, H=64, OUT=60, H2=128
#define B_    64
#define NA_   49
#define NM_   19
#define P_    128
#define OUT_  60
#define KP    136   // padded row stride in bf16 elements (+8 kills 256B-stride conflicts)

typedef __bf16 bf16x8 __attribute__((ext_vector_type(8)));
typedef float  f32x16 __attribute__((ext_vector_type(16)));
typedef unsigned short ushort_t;

__device__ __forceinline__ unsigned int cvt_pk_bf16(float lo, float hi) {
  unsigned int r;
  asm("v_cvt_pk_bf16_f32 %0, %1, %2" : "=v"(r) : "v"(lo), "v"(hi));
  return r;
}

__device__ __forceinline__ f32x16 zero16() {
  f32x16 z;
#pragma unroll
  for (int i = 0; i < 16; ++i) z[i] = 0.f;
  return z;
}

// ---------------------------------------------------------------------------
// SubNetwork via MFMA, transposed orientation: D = W^T (A) x^T (B).
//   v_mfma_f32_32x32x16_bf16 layouts:
//     A: row = lane&31 (channel), k = (lane>>5)*8 + j  (contiguous 8 -> b128)
//     B: col = lane&31 (graph-row), k = (lane>>5)*8 + j (contiguous 8 -> b128)
//     D: col = lane&31 (graph-row), row = (reg&3)+8*(reg>>2)+4*(lane>>5) (chan)
//   => each lane holds 32 channels of ONE row (other 32 in lane^32) ->
//      LayerNorm = in-lane adds + one shfl_xor(32).
// X LDS tile [RPAD][KP] bf16 serves as both B-operand source and nmax scratch.
// ---------------------------------------------------------------------------
template<int NODES, int GPB>
__global__ __launch_bounds__(256, 1) void subnet_mfma(
    const float* __restrict__ in_feat,  // [NG][NODES][64] fp32
    const float* __restrict__ w0, const float* __restrict__ b0,
    const float* __restrict__ g0, const float* __restrict__ n0,
    const float* __restrict__ w1, const float* __restrict__ b1,
    const float* __restrict__ g1, const float* __restrict__ n1,
    const float* __restrict__ w2, const float* __restrict__ b2,
    const float* __restrict__ g2, const float* __restrict__ n2,
    float* __restrict__ out_feats, int out_offset)
{
  constexpr int ROWS = NODES * GPB;
  constexpr int MT   = (ROWS + 31) / 32;   // 32-row M..tiles (N of the mfma)
  constexpr int RPAD = MT * 32;

  __shared__ __align__(16) __bf16 Xs[RPAD * KP];        // activations [row][k]
  __shared__ __align__(16) __bf16 WTs[3 * 64 * KP];     // W^T per layer [c][k]
  __shared__ __align__(16) float Pb[3][64], Pg[3][64], Pn[3][64];

  const int tid  = threadIdx.x;
  const int lane = tid & 63;
  const int wid  = tid >> 6;
  const int lr   = lane & 31;
  const int hi8  = (lane >> 5) * 8;
  const int ch4  = (lane >> 5) * 4;
  const int gbase = blockIdx.x * GPB;

  // ---- stage input features (bf16) ----
  {
    const int NF4 = ROWS * 16;
    for (int i = tid; i < NF4; i += 256) {
      int row = i >> 4, k4 = (i & 15) * 4;
      float4 v = *(const float4*)&in_feat[((size_t)gbase * NODES + row) * 64 + k4];
      uint2 u; u.x = cvt_pk_bf16(v.x, v.y); u.y = cvt_pk_bf16(v.z, v.w);
      *(uint2*)&Xs[row * KP + k4] = u;
    }
    // zero the pad rows completely (deterministic, no NaNs anywhere)
    const int PADU = (RPAD - ROWS) * KP / 2;
    unsigned int* Xp = (unsigned int*)&Xs[ROWS * KP];
    for (int i = tid; i < PADU; i += 256) Xp[i] = 0u;
  }
  // ---- stage W^T (bf16) for all 3 layers + norm params ----
  {
    const float* Wg[3] = { w0, w1, w2 };
    for (int l = 0; l < 3; ++l) {
      const int Kl = l ? 128 : 64;
      const float* W = Wg[l];
      __bf16* WT = &WTs[l * 64 * KP];
      const int cnt = (Kl / 2) * 64;
      for (int i = tid; i < cnt; i += 256) {
        int k2 = i >> 6, c = i & 63;
        float a = W[(2 * k2) * 64 + c];
        float b = W[(2 * k2 + 1) * 64 + c];
        *(unsigned int*)&WT[c * KP + 2 * k2] = cvt_pk_bf16(a, b);
      }
    }
    const float* Bg[3] = { b0, b1, b2 };
    const float* Gg[3] = { g0, g1, g2 };
    const float* Ng[3] = { n0, n1, n2 };
    if (tid < 64) {
      for (int l = 0; l < 3; ++l) {
        Pb[l][tid] = Bg[l][tid];
        Pg[l][tid] = Gg[l][tid];
        Pn[l][tid] = Ng[l][tid];
      }
    }
  }
  __syncthreads();

#pragma unroll
  for (int layer = 0; layer < 3; ++layer) {
    const int KS = (layer == 0) ? 4 : 8;   // K/16 steps
    const __bf16* WT = &WTs[layer * 64 * KP];

    // preload A-fragments (W^T): afr[mt][ks]
    bf16x8 afr[2][8];
#pragma unroll
    for (int mt = 0; mt < 2; ++mt)
#pragma unroll
      for (int ks = 0; ks < 8; ++ks)
        if (ks < KS)
          afr[mt][ks] = *(const bf16x8*)&WT[(mt * 32 + lr) * KP + ks * 16 + hi8];

    // per-lane param registers: index [mt][reg] where reg=(b*4+a), ch=mt*32+8b+4*(lane>>5)+a
    float pbf[2][16], pgf[2][16], pnf[2][16];
#pragma unroll
    for (int mt = 0; mt < 2; ++mt)
#pragma unroll
      for (int b = 0; b < 4; ++b) {
        float4 t;
        t = *(const float4*)&Pb[layer][mt * 32 + 8 * b + ch4];
        pbf[mt][4*b+0]=t.x; pbf[mt][4*b+1]=t.y; pbf[mt][4*b+2]=t.z; pbf[mt][4*b+3]=t.w;
        t = *(const float4*)&Pg[layer][mt * 32 + 8 * b + ch4];
        pgf[mt][4*b+0]=t.x; pgf[mt][4*b+1]=t.y; pgf[mt][4*b+2]=t.z; pgf[mt][4*b+3]=t.w;
        t = *(const float4*)&Pn[layer][mt * 32 + 8 * b + ch4];
        pnf[mt][4*b+0]=t.x; pnf[mt][4*b+1]=t.y; pnf[mt][4*b+2]=t.z; pnf[mt][4*b+3]=t.w;
      }

    for (int nt = wid; nt < MT; nt += 4) {
      const int br = nt * 32 + lr;           // this lane's graph-row
      f32x16 accA0 = zero16(), accA1 = zero16();
      f32x16 accB0 = zero16(), accB1 = zero16();
#pragma unroll
      for (int ks = 0; ks < 8; ++ks) {
        if (ks < KS) {
          bf16x8 bfr = *(const bf16x8*)&Xs[br * KP + ks * 16 + hi8];
          if (ks & 1) {
            accB0 = __builtin_amdgcn_mfma_f32_32x32x16_bf16(afr[0][ks], bfr, accB0, 0, 0, 0);
            accB1 = __builtin_amdgcn_mfma_f32_32x32x16_bf16(afr[1][ks], bfr, accB1, 0, 0, 0);
          } else {
            accA0 = __builtin_amdgcn_mfma_f32_32x32x16_bf16(afr[0][ks], bfr, accA0, 0, 0, 0);
            accA1 = __builtin_amdgcn_mfma_f32_32x32x16_bf16(afr[1][ks], bfr, accA1, 0, 0, 0);
          }
        }
      }
      f32x16 acc0 = accA0 + accB0;
      f32x16 acc1 = accA1 + accB1;

      // ---- bias + LayerNorm(64) fully in-register ----
      float v[2][16];
      float s = 0.f, q = 0.f;
#pragma unroll
      for (int r = 0; r < 16; ++r) {
        v[0][r] = acc0[r] + pbf[0][r];
        v[1][r] = acc1[r] + pbf[1][r];
        s += v[0][r] + v[1][r];
        q = fmaf(v[0][r], v[0][r], q);
        q = fmaf(v[1][r], v[1][r], q);
      }
      s += __shfl_xor(s, 32);
      q += __shfl_xor(q, 32);
      float mu   = s * 0.015625f;
      float rstd = rsqrtf(fmaf(q, 0.015625f, -mu * mu) + 1e-5f);

      // ---- gamma/beta + ReLU, pack bf16, write h to X[row][ch] ----
#pragma unroll
      for (int mt = 0; mt < 2; ++mt) {
#pragma unroll
        for (int b = 0; b < 4; ++b) {
          float h0 = fmaxf(0.f, fmaf((v[mt][4*b+0] - mu) * rstd, pgf[mt][4*b+0], pnf[mt][4*b+0]));
          float h1 = fmaxf(0.f, fmaf((v[mt][4*b+1] - mu) * rstd, pgf[mt][4*b+1], pnf[mt][4*b+1]));
          float h2 = fmaxf(0.f, fmaf((v[mt][4*b+2] - mu) * rstd, pgf[mt][4*b+2], pnf[mt][4*b+2]));
          float h3 = fmaxf(0.f, fmaf((v[mt][4*b+3] - mu) * rstd, pgf[mt][4*b+3], pnf[mt][4*b+3]));
          uint2 u; u.x = cvt_pk_bf16(h0, h1); u.y = cvt_pk_bf16(h2, h3);
          *(uint2*)&Xs[br * KP + mt * 32 + 8 * b + ch4] = u;
        }
      }
    }
    __syncthreads();

    if (layer < 2) {
      // neighbor-max (top-2 trick); h>=0 so bf16 bits compare as uint16
      if (tid < GPB * 16) {
        const int g = tid >> 4, c4 = (tid & 15) * 4;
        const ushort_t* Xu = (const ushort_t*)Xs;
        ushort_t* Xw = (ushort_t*)Xs;
        const int base = g * NODES * KP + c4;
        unsigned int m1[4] = {0,0,0,0}, m2[4] = {0,0,0,0};
        for (int n = 0; n < NODES; ++n) {
          uint2 u = *(const uint2*)&Xu[base + n * KP];
          unsigned int x[4] = { u.x & 0xFFFFu, u.x >> 16, u.y & 0xFFFFu, u.y >> 16 };
#pragma unroll
          for (int j = 0; j < 4; ++j) {
            if (x[j] > m1[j]) { m2[j] = m1[j]; m1[j] = x[j]; }
            else if (x[j] > m2[j]) m2[j] = x[j];
          }
        }
        for (int n = 0; n < NODES; ++n) {
          uint2 u = *(const uint2*)&Xu[base + n * KP];
          unsigned int x[4] = { u.x & 0xFFFFu, u.x >> 16, u.y & 0xFFFFu, u.y >> 16 };
          unsigned int w[4];
#pragma unroll
          for (int j = 0; j < 4; ++j) w[j] = (x[j] == m1[j]) ? m2[j] : m1[j];
          uint2 o; o.x = w[0] | (w[1] << 16); o.y = w[2] | (w[3] << 16);
          *(uint2*)&Xw[base + n * KP + 64] = o;
        }
      }
      __syncthreads();
    } else {
      // poly = max over nodes; both halves equal max_n h (N >= 2)
      if (tid < GPB * 16) {
        const int g = tid >> 4, c4 = (tid & 15) * 4;
        const ushort_t* Xu = (const ushort_t*)Xs;
        const int base = g * NODES * KP + c4;
        unsigned int m1[4] = {0,0,0,0};
        for (int n = 0; n < NODES; ++n) {
          uint2 u = *(const uint2*)&Xu[base + n * KP];
          unsigned int x[4] = { u.x & 0xFFFFu, u.x >> 16, u.y & 0xFFFFu, u.y >> 16 };
#pragma unroll
          for (int j = 0; j < 4; ++j) m1[j] = (x[j] > m1[j]) ? x[j] : m1[j];
        }
        float4 o;
        o.x = __uint_as_float(m1[0] << 16);
        o.y = __uint_as_float(m1[1] << 16);
        o.z = __uint_as_float(m1[2] << 16);
        o.w = __uint_as_float(m1[3] << 16);
        size_t slot = (size_t)(out_offset + gbase + g);
        *(float4*)&out_feats[slot * 128 + c4] = o;
        *(float4*)&out_feats[slot * 128 + 64 + c4] = o;
      }
    }
  }
}

// ---------------------------------------------------------------------------
// GAT (only destination node 0 is read) + readout MLP. One block per batch b.
// ---------------------------------------------------------------------------
__global__ __launch_bounds__(256) void gat_kernel(
    const float* __restrict__ feats,    // [129][B][128] fp32
    const float* __restrict__ fcw,      // [128][128]
    const float* __restrict__ attnw,    // [256]
    const float* __restrict__ mlpw,     // [128][60]
    const float* __restrict__ mlpb,     // [60]
    float* __restrict__ out)            // [B][60]
{
  const int b = blockIdx.x, tid = threadIdx.x;
  __shared__ float asrc[128], adst[128], was[128], wad[128];
  __shared__ float si[130];
  __shared__ float alpha[128], red[8], ubuf[128], hg[128];

  if (tid < 128) { asrc[tid] = attnw[tid]; adst[tid] = attnw[128 + tid]; }
  __syncthreads();

  if (tid < 128) {
    float s1 = 0.f, s2 = 0.f;
    for (int c = 0; c < 128; ++c) {
      float w = fcw[tid * 128 + c];
      s1 += w * asrc[c];
      s2 += w * adst[c];
    }
    was[tid] = s1; wad[tid] = s2;
  }
  __syncthreads();

  if (tid < 130) {
    const float* wa = (tid == 129) ? wad : was;
    int node = (tid == 129) ? 0 : tid;
    const float* fr = feats + ((size_t)node * B_ + b) * 128;
    float s = 0.f;
    for (int k = 0; k < 128; k += 4) {
      float4 f = *(const float4*)&fr[k];
      s += f.x * wa[k] + f.y * wa[k + 1] + f.z * wa[k + 2] + f.w * wa[k + 3];
    }
    si[tid] = s;
  }
  __syncthreads();

  float d0 = si[129];
  float e = -3.4e38f;
  if (tid < 128) {
    float x = si[tid + 1] + d0;
    e = (x > 0.f) ? x : 0.01f * x;
  }
  float m = e;
#pragma unroll
  for (int off = 32; off; off >>= 1) m = fmaxf(m, __shfl_xor(m, off));
  if ((tid & 63) == 0) red[tid >> 6] = m;
  __syncthreads();
  float mx = fmaxf(red[0], red[1]);
  float p = (tid < 128) ? expf(e - mx) : 0.f;
  float s = p;
#pragma unroll
  for (int off = 32; off; off >>= 1) s += __shfl_xor(s, off);
  if ((tid & 63) == 0) red[4 + (tid >> 6)] = s;
  __syncthreads();
  float denom = red[4] + red[5];
  if (tid < 128) alpha[tid] = p / denom;
  __syncthreads();

  if (tid < 128) {
    float u = 0.f;
    for (int t = 0; t < 128; ++t)
      u += alpha[t] * feats[((size_t)(t + 1) * B_ + b) * 128 + tid];
    ubuf[tid] = u;
  }
  __syncthreads();

  if (tid < 128) {
    float hh = 0.f;
    for (int k = 0; k < 128; ++k) hh += ubuf[k] * fcw[k * 128 + tid];
    hg[tid] = hh;
  }
  __syncthreads();

  if (tid < OUT_) {
    float o = mlpb[tid];
    for (int c = 0; c < 128; ++c) o += hg[c] * mlpw[c * OUT_ + tid];
    out[b * OUT_ + tid] = o;
  }
}

// ---------------------------------------------------------------------------
extern "C" void kernel_launch(void* const* d_in, const int* in_sizes, int n_in,
                              void* d_out, int out_size, void* d_ws, size_t ws_size,
                              hipStream_t stream) {
  (void)in_sizes; (void)n_in; (void)out_size; (void)ws_size;

  const float* agent = (const float*)d_in[0];   // [B][NA][64]
  const float* mapf  = (const float*)d_in[1];   // [P][B][NM][64]
  // d_in[2] = map_mask (all ones, unused)

  const float* aw0 = (const float*)d_in[3];
  const float* ab0 = (const float*)d_in[4];
  const float* ag0 = (const float*)d_in[5];
  const float* an0 = (const float*)d_in[6];
  const float* aw1 = (const float*)d_in[7];
  const float* ab1 = (const float*)d_in[8];
  const float* ag1 = (const float*)d_in[9];
  const float* an1 = (const float*)d_in[10];
  const float* aw2 = (const float*)d_in[11];
  const float* ab2 = (const float*)d_in[12];
  const float* ag2 = (const float*)d_in[13];
  const float* an2 = (const float*)d_in[14];

  const float* mw0 = (const float*)d_in[15];
  const float* mb0 = (const float*)d_in[16];
  const float* mg0 = (const float*)d_in[17];
  const float* mn0 = (const float*)d_in[18];
  const float* mw1 = (const float*)d_in[19];
  const float* mb1 = (const float*)d_in[20];
  const float* mg1 = (const float*)d_in[21];
  const float* mn1 = (const float*)d_in[22];
  const float* mw2 = (const float*)d_in[23];
  const float* mb2 = (const float*)d_in[24];
  const float* mg2 = (const float*)d_in[25];
  const float* mn2 = (const float*)d_in[26];

  const float* fcw   = (const float*)d_in[27];
  const float* attnw = (const float*)d_in[28];
  const float* mlpw  = (const float*)d_in[29];
  const float* mlpb  = (const float*)d_in[30];

  float* feats = (float*)d_ws;                 // [129][B][128] fp32 = 4.2 MB
  float* out = (float*)d_out;

  // map subnet: 8192 graphs, 16 per block; poly -> slots [B .. B+8191]
  subnet_mfma<NM_, 16><<<(P_ * B_) / 16, 256, 0, stream>>>(
      mapf, mw0, mb0, mg0, mn0, mw1, mb1, mg1, mn1, mw2, mb2, mg2, mn2,
      feats, B_);

  // agent subnet: 64 graphs, 4 per block; poly -> slots [0 .. B-1]
  subnet_mfma<NA_, 4><<<B_ / 4, 256, 0, stream>>>(
      agent, aw0, ab0, ag0, an0, aw1, ab1, ag1, an1, aw2, ab2, ag2, an2,
      feats, 0);

  // GAT column-0 + MLP readout
  gat_kernel<<<B_, 256, 0, stream>>>(feats, fcw, attnw, mlpw, mlpb, out);
}

// Round 5
// 87.933 us; speedup vs baseline: 3.0523x; 1.2893x over previous
//
#include <hip/hip_runtime.h>
#include <stdint.h>

// Problem dims (VectorNet): B=64, NA=49, NM=19, P=128, IN=64, H=64, OUT=60, H2=128
#define B_    64
#define NA_   49
#define NM_   19
#define P_    128
#define OUT_  60
#define KP    136       // padded row stride in bf16 elements
#define AGRID 32        // agent blocks: 64 graphs / GPB=2
#define MGRID 1024      // map blocks: 8192 graphs / GPB=8
// dynamic LDS: map instantiation (RPAD=160) is the larger one
#define SMEM_BYTES (160 * KP * 2 + 9 * 64 * 4)

typedef __bf16 bf16x8 __attribute__((ext_vector_type(8)));
typedef float  f32x16 __attribute__((ext_vector_type(16)));
typedef unsigned short ushort_t;

__device__ __forceinline__ unsigned int cvt_pk_bf16(float lo, float hi) {
  unsigned int r;
  asm("v_cvt_pk_bf16_f32 %0, %1, %2" : "=v"(r) : "v"(lo), "v"(hi));
  return r;
}

__device__ __forceinline__ f32x16 zero16() {
  f32x16 z;
#pragma unroll
  for (int i = 0; i < 16; ++i) z[i] = 0.f;
  return z;
}

// ---------------------------------------------------------------------------
// SubNetwork via MFMA, transposed orientation: D = W^T (A) x^T (B).
//   v_mfma_f32_32x32x16_bf16 layouts (verified in round 3):
//     A: row = lane&31 (channel), k = (lane>>5)*8 + j
//     B: col = lane&31 (graph-row), k = (lane>>5)*8 + j
//     D: col = lane&31 (graph-row), chan = (reg&3)+8*(reg>>2)+4*(lane>>5)
//   => lane holds 32 channels of ONE row; LN = in-lane adds + one shfl_xor(32).
// W^T fragments are loaded from GLOBAL (L2-resident) into registers per wave;
// no W staging in LDS -> 44.8 KB LDS -> 3 blocks/CU.
// ---------------------------------------------------------------------------
template<int NODES, int GPB>
__device__ __forceinline__ void subnet_body(
    const float* __restrict__ in_feat,  // [NG][NODES][64] fp32
    const float* __restrict__ w0, const float* __restrict__ b0,
    const float* __restrict__ g0, const float* __restrict__ n0,
    const float* __restrict__ w1, const float* __restrict__ b1,
    const float* __restrict__ g1, const float* __restrict__ n1,
    const float* __restrict__ w2, const float* __restrict__ b2,
    const float* __restrict__ g2, const float* __restrict__ n2,
    float* __restrict__ out_feats, int out_offset, int bid, char* smem)
{
  constexpr int ROWS = NODES * GPB;
  constexpr int MT   = (ROWS + 31) / 32;
  constexpr int RPAD = MT * 32;

  __bf16* Xs = (__bf16*)smem;                 // [RPAD][KP] activations
  float*  Pb = (float*)(smem + RPAD * KP * 2);  // [3][64] bias
  float*  Pg = Pb + 192;                        // [3][64] gamma
  float*  Pn = Pg + 192;                        // [3][64] beta

  const int tid  = threadIdx.x;
  const int lane = tid & 63;
  const int wid  = tid >> 6;
  const int lr   = lane & 31;
  const int hi8  = (lane >> 5) * 8;
  const int ch4  = (lane >> 5) * 4;
  const int gbase = bid * GPB;

  // ---- stage input features (bf16) + zero pad rows + stage norm params ----
  {
    const int NF4 = ROWS * 16;
    for (int i = tid; i < NF4; i += 256) {
      int row = i >> 4, k4 = (i & 15) * 4;
      float4 v = *(const float4*)&in_feat[((size_t)gbase * NODES + row) * 64 + k4];
      uint2 u; u.x = cvt_pk_bf16(v.x, v.y); u.y = cvt_pk_bf16(v.z, v.w);
      *(uint2*)&Xs[row * KP + k4] = u;
    }
    const int PADU = (RPAD - ROWS) * KP / 2;
    unsigned int* Xp = (unsigned int*)&Xs[ROWS * KP];
    for (int i = tid; i < PADU; i += 256) Xp[i] = 0u;
    if (tid < 64) {
      const float* Bg[3] = { b0, b1, b2 };
      const float* Gg[3] = { g0, g1, g2 };
      const float* Ng[3] = { n0, n1, n2 };
      for (int l = 0; l < 3; ++l) {
        Pb[l * 64 + tid] = Bg[l][tid];
        Pg[l * 64 + tid] = Gg[l][tid];
        Pn[l * 64 + tid] = Ng[l][tid];
      }
    }
  }
  __syncthreads();

#pragma unroll
  for (int layer = 0; layer < 3; ++layer) {
    const int KS = (layer == 0) ? 4 : 8;   // K/16 steps
    const float* Wl = (layer == 0) ? w0 : (layer == 1 ? w1 : w2);

    // preload A-fragments (W^T) from global; coalesced per-j (32 lanes x 4B)
    bf16x8 afr[2][8];
#pragma unroll
    for (int mt = 0; mt < 2; ++mt)
#pragma unroll
      for (int ks = 0; ks < 8; ++ks)
        if (ks < KS) {
          float f[8];
#pragma unroll
          for (int j = 0; j < 8; ++j)
            f[j] = Wl[(ks * 16 + hi8 + j) * 64 + mt * 32 + lr];
          union { unsigned int u[4]; bf16x8 v; } t;
          t.u[0] = cvt_pk_bf16(f[0], f[1]);
          t.u[1] = cvt_pk_bf16(f[2], f[3]);
          t.u[2] = cvt_pk_bf16(f[4], f[5]);
          t.u[3] = cvt_pk_bf16(f[6], f[7]);
          afr[mt][ks] = t.v;
        }

    for (int nt = wid; nt < MT; nt += 4) {
      const int br = nt * 32 + lr;           // this lane's graph-row
      f32x16 acc0 = zero16(), acc1 = zero16();
#pragma unroll
      for (int ks = 0; ks < 8; ++ks)
        if (ks < KS) {
          bf16x8 bfr = *(const bf16x8*)&Xs[br * KP + ks * 16 + hi8];
          acc0 = __builtin_amdgcn_mfma_f32_32x32x16_bf16(afr[0][ks], bfr, acc0, 0, 0, 0);
          acc1 = __builtin_amdgcn_mfma_f32_32x32x16_bf16(afr[1][ks], bfr, acc1, 0, 0, 0);
        }

      // ---- bias + LayerNorm(64) fully in-register ----
      float v[2][16];
#pragma unroll
      for (int r = 0; r < 16; ++r) { v[0][r] = acc0[r]; v[1][r] = acc1[r]; }
#pragma unroll
      for (int mt = 0; mt < 2; ++mt)
#pragma unroll
        for (int b = 0; b < 4; ++b) {
          float4 tb = *(const float4*)&Pb[layer * 64 + mt * 32 + 8 * b + ch4];
          v[mt][4*b+0] += tb.x; v[mt][4*b+1] += tb.y;
          v[mt][4*b+2] += tb.z; v[mt][4*b+3] += tb.w;
        }
      float s = 0.f, q = 0.f;
#pragma unroll
      for (int r = 0; r < 16; ++r) {
        s += v[0][r] + v[1][r];
        q = fmaf(v[0][r], v[0][r], q);
        q = fmaf(v[1][r], v[1][r], q);
      }
      s += __shfl_xor(s, 32);
      q += __shfl_xor(q, 32);
      float mu   = s * 0.015625f;
      float rstd = rsqrtf(fmaf(q, 0.015625f, -mu * mu) + 1e-5f);

      // ---- gamma/beta + ReLU, pack bf16, write h to X[row][ch] ----
#pragma unroll
      for (int mt = 0; mt < 2; ++mt)
#pragma unroll
        for (int b = 0; b < 4; ++b) {
          float4 tg = *(const float4*)&Pg[layer * 64 + mt * 32 + 8 * b + ch4];
          float4 tn = *(const float4*)&Pn[layer * 64 + mt * 32 + 8 * b + ch4];
          float h0 = fmaxf(0.f, fmaf((v[mt][4*b+0] - mu) * rstd, tg.x, tn.x));
          float h1 = fmaxf(0.f, fmaf((v[mt][4*b+1] - mu) * rstd, tg.y, tn.y));
          float h2 = fmaxf(0.f, fmaf((v[mt][4*b+2] - mu) * rstd, tg.z, tn.z));
          float h3 = fmaxf(0.f, fmaf((v[mt][4*b+3] - mu) * rstd, tg.w, tn.w));
          uint2 u; u.x = cvt_pk_bf16(h0, h1); u.y = cvt_pk_bf16(h2, h3);
          *(uint2*)&Xs[br * KP + mt * 32 + 8 * b + ch4] = u;
        }
    }
    __syncthreads();

    if (layer < 2) {
      // neighbor-max (top-2); h>=0 so bf16 bits compare as uint16.
      // 256 threads, 2 channels each (packed uint).
      const ushort_t* Xu = (const ushort_t*)Xs;
      ushort_t* Xw = (ushort_t*)Xs;
      for (int s2 = tid; s2 < GPB * 32; s2 += 256) {
        const int g = s2 >> 5, c2 = (s2 & 31) * 2;
        const int base = g * NODES * KP + c2;
        unsigned int m1a = 0, m2a = 0, m1b = 0, m2b = 0;
        for (int n = 0; n < NODES; ++n) {
          unsigned int u = *(const unsigned int*)&Xu[base + n * KP];
          unsigned int a = u & 0xFFFFu, c = u >> 16;
          if (a > m1a) { m2a = m1a; m1a = a; } else if (a > m2a) m2a = a;
          if (c > m1b) { m2b = m1b; m1b = c; } else if (c > m2b) m2b = c;
        }
        for (int n = 0; n < NODES; ++n) {
          unsigned int u = *(const unsigned int*)&Xu[base + n * KP];
          unsigned int a = u & 0xFFFFu, c = u >> 16;
          unsigned int wa = (a == m1a) ? m2a : m1a;
          unsigned int wb = (c == m1b) ? m2b : m1b;
          *(unsigned int*)&Xw[base + n * KP + 64] = wa | (wb << 16);
        }
      }
      __syncthreads();
    } else {
      // poly = max over nodes; both output halves equal max_n h (N >= 2)
      const ushort_t* Xu = (const ushort_t*)Xs;
      for (int s2 = tid; s2 < GPB * 32; s2 += 256) {
        const int g = s2 >> 5, c2 = (s2 & 31) * 2;
        const int base = g * NODES * KP + c2;
        unsigned int m1a = 0, m1b = 0;
        for (int n = 0; n < NODES; ++n) {
          unsigned int u = *(const unsigned int*)&Xu[base + n * KP];
          unsigned int a = u & 0xFFFFu, c = u >> 16;
          m1a = a > m1a ? a : m1a;
          m1b = c > m1b ? c : m1b;
        }
        float2 o = make_float2(__uint_as_float(m1a << 16),
                               __uint_as_float(m1b << 16));
        size_t slot = (size_t)(out_offset + gbase + g);
        *(float2*)&out_feats[slot * 128 + c2] = o;
        *(float2*)&out_feats[slot * 128 + 64 + c2] = o;
      }
    }
  }
}

__global__ __launch_bounds__(256, 3) void subnet_all(
    const float* __restrict__ agent, const float* __restrict__ mapf,
    const float* __restrict__ aw0, const float* __restrict__ ab0,
    const float* __restrict__ ag0, const float* __restrict__ an0,
    const float* __restrict__ aw1, const float* __restrict__ ab1,
    const float* __restrict__ ag1, const float* __restrict__ an1,
    const float* __restrict__ aw2, const float* __restrict__ ab2,
    const float* __restrict__ ag2, const float* __restrict__ an2,
    const float* __restrict__ mw0, const float* __restrict__ mb0,
    const float* __restrict__ mg0, const float* __restrict__ mn0,
    const float* __restrict__ mw1, const float* __restrict__ mb1,
    const float* __restrict__ mg1, const float* __restrict__ mn1,
    const float* __restrict__ mw2, const float* __restrict__ mb2,
    const float* __restrict__ mg2, const float* __restrict__ mn2,
    float* __restrict__ feats)
{
  extern __shared__ __align__(16) char smem[];
  if (blockIdx.x < AGRID) {
    subnet_body<NA_, 2>(agent, aw0, ab0, ag0, an0, aw1, ab1, ag1, an1,
                        aw2, ab2, ag2, an2, feats, 0, blockIdx.x, smem);
  } else {
    subnet_body<NM_, 8>(mapf, mw0, mb0, mg0, mn0, mw1, mb1, mg1, mn1,
                        mw2, mb2, mg2, mn2, feats, B_, blockIdx.x - AGRID, smem);
  }
}

// ---------------------------------------------------------------------------
// GAT (only destination node 0 is read) + readout MLP. One block per batch b.
// ---------------------------------------------------------------------------
__global__ __launch_bounds__(256) void gat_kernel(
    const float* __restrict__ feats,    // [129][B][128] fp32
    const float* __restrict__ fcw,      // [128][128]
    const float* __restrict__ attnw,    // [256]
    const float* __restrict__ mlpw,     // [128][60]
    const float* __restrict__ mlpb,     // [60]
    float* __restrict__ out)            // [B][60]
{
  const int b = blockIdx.x, tid = threadIdx.x;
  __shared__ float asrc[128], adst[128], was[128], wad[128];
  __shared__ float si[130];
  __shared__ float alpha[128], red[8], ubuf[128], hg[128];

  if (tid < 128) { asrc[tid] = attnw[tid]; adst[tid] = attnw[128 + tid]; }
  __syncthreads();

  if (tid < 128) {
    float s1 = 0.f, s2 = 0.f;
    for (int c = 0; c < 128; ++c) {
      float w = fcw[tid * 128 + c];
      s1 += w * asrc[c];
      s2 += w * adst[c];
    }
    was[tid] = s1; wad[tid] = s2;
  }
  __syncthreads();

  if (tid < 130) {
    const float* wa = (tid == 129) ? wad : was;
    int node = (tid == 129) ? 0 : tid;
    const float* fr = feats + ((size_t)node * B_ + b) * 128;
    float s = 0.f;
    for (int k = 0; k < 128; k += 4) {
      float4 f = *(const float4*)&fr[k];
      s += f.x * wa[k] + f.y * wa[k + 1] + f.z * wa[k + 2] + f.w * wa[k + 3];
    }
    si[tid] = s;
  }
  __syncthreads();

  float d0 = si[129];
  float e = -3.4e38f;
  if (tid < 128) {
    float x = si[tid + 1] + d0;
    e = (x > 0.f) ? x : 0.01f * x;
  }
  float m = e;
#pragma unroll
  for (int off = 32; off; off >>= 1) m = fmaxf(m, __shfl_xor(m, off));
  if ((tid & 63) == 0) red[tid >> 6] = m;
  __syncthreads();
  float mx = fmaxf(red[0], red[1]);
  float p = (tid < 128) ? expf(e - mx) : 0.f;
  float s = p;
#pragma unroll
  for (int off = 32; off; off >>= 1) s += __shfl_xor(s, off);
  if ((tid & 63) == 0) red[4 + (tid >> 6)] = s;
  __syncthreads();
  float denom = red[4] + red[5];
  if (tid < 128) alpha[tid] = p / denom;
  __syncthreads();

  if (tid < 128) {
    float u = 0.f;
    for (int t = 0; t < 128; ++t)
      u += alpha[t] * feats[((size_t)(t + 1) * B_ + b) * 128 + tid];
    ubuf[tid] = u;
  }
  __syncthreads();

  if (tid < 128) {
    float hh = 0.f;
    for (int k = 0; k < 128; ++k) hh += ubuf[k] * fcw[k * 128 + tid];
    hg[tid] = hh;
  }
  __syncthreads();

  if (tid < OUT_) {
    float o = mlpb[tid];
    for (int c = 0; c < 128; ++c) o += hg[c] * mlpw[c * OUT_ + tid];
    out[b * OUT_ + tid] = o;
  }
}

// ---------------------------------------------------------------------------
extern "C" void kernel_launch(void* const* d_in, const int* in_sizes, int n_in,
                              void* d_out, int out_size, void* d_ws, size_t ws_size,
                              hipStream_t stream) {
  (void)in_sizes; (void)n_in; (void)out_size; (void)ws_size;

  const float* agent = (const float*)d_in[0];   // [B][NA][64]
  const float* mapf  = (const float*)d_in[1];   // [P][B][NM][64]
  // d_in[2] = map_mask (all ones, unused)

  const float* aw0 = (const float*)d_in[3];
  const float* ab0 = (const float*)d_in[4];
  const float* ag0 = (const float*)d_in[5];
  const float* an0 = (const float*)d_in[6];
  const float* aw1 = (const float*)d_in[7];
  const float* ab1 = (const float*)d_in[8];
  const float* ag1 = (const float*)d_in[9];
  const float* an1 = (const float*)d_in[10];
  const float* aw2 = (const float*)d_in[11];
  const float* ab2 = (const float*)d_in[12];
  const float* ag2 = (const float*)d_in[13];
  const float* an2 = (const float*)d_in[14];

  const float* mw0 = (const float*)d_in[15];
  const float* mb0 = (const float*)d_in[16];
  const float* mg0 = (const float*)d_in[17];
  const float* mn0 = (const float*)d_in[18];
  const float* mw1 = (const float*)d_in[19];
  const float* mb1 = (const float*)d_in[20];
  const float* mg1 = (const float*)d_in[21];
  const float* mn1 = (const float*)d_in[22];
  const float* mw2 = (const float*)d_in[23];
  const float* mb2 = (const float*)d_in[24];
  const float* mg2 = (const float*)d_in[25];
  const float* mn2 = (const float*)d_in[26];

  const float* fcw   = (const float*)d_in[27];
  const float* attnw = (const float*)d_in[28];
  const float* mlpw  = (const float*)d_in[29];
  const float* mlpb  = (const float*)d_in[30];

  float* feats = (float*)d_ws;                 // [129][B][128] fp32 = 4.2 MB
  float* out = (float*)d_out;

  // fused agent(32 blocks) + map(1024 blocks) subnet dispatch
  subnet_all<<<AGRID + MGRID, 256, SMEM_BYTES, stream>>>(
      agent, mapf,
      aw0, ab0, ag0, an0, aw1, ab1, ag1, an1, aw2, ab2, ag2, an2,
      mw0, mb0, mg0, mn0, mw1, mb1, mg1, mn1, mw2, mb2, mg2, mn2,
      feats);

  // GAT column-0 + MLP readout
  gat_kernel<<<B_, 256, 0, stream>>>(feats, fcw, attnw, mlpw, mlpb, out);
}

// Round 7
// 83.830 us; speedup vs baseline: 3.2017x; 1.0490x over previous
//
#include <hip/hip_runtime.h>
#include <stdint.h>

// Problem dims (VectorNet): B=64, NA=49, NM=19, P=128, IN=64, H=64, OUT=60, H2=128
#define B_    64
#define NA_   49
#define NM_   19
#define P_    128
#define OUT_  60
#define KP    136                      // padded row stride (bf16) — keeps 16B align, breaks 256B bank wrap
#define XROWS 92                       // map: 4 waves x 20 rows + 31-row read overhang (60+31=91)
#define AGRID 64                       // agent: 1 graph per block
#define MGRID 2048                     // map: 4 graphs per block (1 per wave)
#define XBYTES (XROWS * KP * 2)        // 25024
#define WBYTES (64 * KP * 2)           // 17408 per layer (W^T bf16)
#define SMEM_BYTES (XBYTES + 3 * WBYTES + 9 * 64 * 4)   // 79552 -> 2 blocks/CU

typedef __bf16 bf16x8 __attribute__((ext_vector_type(8)));
typedef float  f32x16 __attribute__((ext_vector_type(16)));
typedef unsigned short ushort_t;

__device__ __forceinline__ unsigned int cvt_pk_bf16(float lo, float hi) {
  unsigned int r;
  asm("v_cvt_pk_bf16_f32 %0, %1, %2" : "=v"(r) : "v"(lo), "v"(hi));
  return r;
}

__device__ __forceinline__ f32x16 zero16() {
  f32x16 z;
#pragma unroll
  for (int i = 0; i < 16; ++i) z[i] = 0.f;
  return z;
}

// ---------------------------------------------------------------------------
// One 32-row x 64-chan layer tile for one wave (verified r3/r5 math):
//   v_mfma_f32_32x32x16_bf16, D = W^T (A) x^T (B)
//     A: row=lane&31 (chan), k=(lane>>5)*8+j ; B: col=lane&31 (graph-row)
//     D: col=lane&31 (row), chan=(reg&3)+8*(reg>>2)+4*(lane>>5)
//   LayerNorm(64) = in-lane adds + one shfl_xor(32). h written back bf16.
//   Lanes lr>=vr produce garbage (contained) and are write-guarded.
// ---------------------------------------------------------------------------
template<int KS>
__device__ __forceinline__ void tile_layer(
    const __bf16* __restrict__ WT,  // [64][KP] this layer's W^T (bf16, LDS)
    __bf16* __restrict__ Xs,        // [XROWS][KP] activations (LDS)
    int xrow0, int vr,
    const float* __restrict__ Pb, const float* __restrict__ Pg,
    const float* __restrict__ Pn)
{
  const int lane = threadIdx.x & 63;
  const int lr   = lane & 31;
  const int hi8  = (lane >> 5) * 8;
  const int ch4  = (lane >> 5) * 4;

  bf16x8 afr[2][KS];
#pragma unroll
  for (int mt = 0; mt < 2; ++mt)
#pragma unroll
    for (int ks = 0; ks < KS; ++ks)
      afr[mt][ks] = *(const bf16x8*)&WT[(mt * 32 + lr) * KP + ks * 16 + hi8];

  const int br = xrow0 + lr;
  f32x16 acc0 = zero16(), acc1 = zero16();
#pragma unroll
  for (int ks = 0; ks < KS; ++ks) {
    bf16x8 bfr = *(const bf16x8*)&Xs[br * KP + ks * 16 + hi8];
    acc0 = __builtin_amdgcn_mfma_f32_32x32x16_bf16(afr[0][ks], bfr, acc0, 0, 0, 0);
    acc1 = __builtin_amdgcn_mfma_f32_32x32x16_bf16(afr[1][ks], bfr, acc1, 0, 0, 0);
  }

  float v[2][16];
#pragma unroll
  for (int r = 0; r < 16; ++r) { v[0][r] = acc0[r]; v[1][r] = acc1[r]; }
#pragma unroll
  for (int mt = 0; mt < 2; ++mt)
#pragma unroll
    for (int b = 0; b < 4; ++b) {
      float4 tb = *(const float4*)&Pb[mt * 32 + 8 * b + ch4];
      v[mt][4*b+0] += tb.x; v[mt][4*b+1] += tb.y;
      v[mt][4*b+2] += tb.z; v[mt][4*b+3] += tb.w;
    }
  float s = 0.f, q = 0.f;
#pragma unroll
  for (int r = 0; r < 16; ++r) {
    s += v[0][r] + v[1][r];
    q = fmaf(v[0][r], v[0][r], q);
    q = fmaf(v[1][r], v[1][r], q);
  }
  s += __shfl_xor(s, 32);
  q += __shfl_xor(q, 32);
  float mu   = s * 0.015625f;
  float rstd = rsqrtf(fmaf(q, 0.015625f, -mu * mu) + 1e-5f);

#pragma unroll
  for (int mt = 0; mt < 2; ++mt)
#pragma unroll
    for (int b = 0; b < 4; ++b) {
      float4 tg = *(const float4*)&Pg[mt * 32 + 8 * b + ch4];
      float4 tn = *(const float4*)&Pn[mt * 32 + 8 * b + ch4];
      float h0 = fmaxf(0.f, fmaf((v[mt][4*b+0] - mu) * rstd, tg.x, tn.x));
      float h1 = fmaxf(0.f, fmaf((v[mt][4*b+1] - mu) * rstd, tg.y, tn.y));
      float h2 = fmaxf(0.f, fmaf((v[mt][4*b+2] - mu) * rstd, tg.z, tn.z));
      float h3 = fmaxf(0.f, fmaf((v[mt][4*b+3] - mu) * rstd, tg.w, tn.w));
      uint2 u; u.x = cvt_pk_bf16(h0, h1); u.y = cvt_pk_bf16(h2, h3);
      if (lr < vr)
        *(uint2*)&Xs[br * KP + mt * 32 + 8 * b + ch4] = u;
    }
}

// wave-private neighbor-max (top-2); lane = channel; h>=0 -> uint16 compare
__device__ __forceinline__ void nmax_wave(__bf16* Xs, int rb, int nn) {
  const int lane = threadIdx.x & 63;
  ushort_t* Xu = (ushort_t*)Xs;
  unsigned int m1 = 0, m2 = 0;
  for (int n = 0; n < nn; ++n) {
    unsigned int x = Xu[(rb + n) * KP + lane];
    if (x > m1) { m2 = m1; m1 = x; } else if (x > m2) m2 = x;
  }
  for (int n = 0; n < nn; ++n) {
    unsigned int x = Xu[(rb + n) * KP + lane];
    Xu[(rb + n) * KP + 64 + lane] = (ushort_t)((x == m1) ? m2 : m1);
  }
}

// poly = max over nodes; both output halves equal max_n h (N>=2); lane=chan
__device__ __forceinline__ void poly_store(__bf16* Xs, int rb, int nn,
                                           float* __restrict__ dst) {
  const int lane = threadIdx.x & 63;
  ushort_t* Xu = (ushort_t*)Xs;
  unsigned int m1 = 0;
  for (int n = 0; n < nn; ++n) {
    unsigned int x = Xu[(rb + n) * KP + lane];
    m1 = x > m1 ? x : m1;
  }
  float f = __uint_as_float(m1 << 16);
  dst[lane] = f;
  dst[64 + lane] = f;
}

// cooperative staging of W^T (3 layers, bf16) + norm params into LDS
__device__ __forceinline__ void stage_wp(
    const float* w0, const float* w1, const float* w2,
    const float* b0, const float* g0, const float* n0,
    const float* b1, const float* g1, const float* n1,
    const float* b2, const float* g2, const float* n2, char* smem)
{
  __bf16* WT = (__bf16*)(smem + XBYTES);
  float*  Pp = (float*)(smem + XBYTES + 3 * WBYTES);
  const int tid = threadIdx.x;
  const float* Wg[3] = { w0, w1, w2 };
#pragma unroll
  for (int l = 0; l < 3; ++l) {
    const int Kl = l ? 128 : 64;
    const float* W = Wg[l];
    __bf16* WTl = WT + l * 64 * KP;
    const int cnt = (Kl / 2) * 64;
    for (int i = tid; i < cnt; i += 256) {
      int k2 = i >> 6, c = i & 63;
      *(unsigned int*)&WTl[c * KP + 2 * k2] =
          cvt_pk_bf16(W[(2 * k2) * 64 + c], W[(2 * k2 + 1) * 64 + c]);
    }
  }
  if (tid < 64) {
    const float* Bg[3] = { b0, b1, b2 };
    const float* Gg[3] = { g0, g1, g2 };
    const float* Ng[3] = { n0, n1, n2 };
#pragma unroll
    for (int l = 0; l < 3; ++l) {
      Pp[l * 192 +       tid] = Bg[l][tid];
      Pp[l * 192 +  64 + tid] = Gg[l][tid];
      Pp[l * 192 + 128 + tid] = Ng[l][tid];
    }
  }
}

// agent neighbor-max: all 4 waves scan 49 nodes (redundant), split writes
__device__ __forceinline__ void nmax_agent(char* smem) {
  __bf16* Xs = (__bf16*)smem;
  ushort_t* Xu = (ushort_t*)Xs;
  const int lane = threadIdx.x & 63, wid = threadIdx.x >> 6;
  unsigned int m1 = 0, m2 = 0;
  for (int n = 0; n < NA_; ++n) {
    unsigned int x = Xu[n * KP + lane];
    if (x > m1) { m2 = m1; m1 = x; } else if (x > m2) m2 = x;
  }
  int n0 = wid * 13, n1 = (n0 + 13 > NA_) ? NA_ : n0 + 13;
  for (int n = n0; n < n1; ++n) {
    unsigned int x = Xu[n * KP + lane];
    Xu[n * KP + 64 + lane] = (ushort_t)((x == m1) ? m2 : m1);
  }
}

// ---------------------------------------------------------------------------
__global__ __launch_bounds__(256, 2) void subnet2(
    const float* __restrict__ agent, const float* __restrict__ mapf,
    const float* __restrict__ aw0, const float* __restrict__ ab0,
    const float* __restrict__ ag0, const float* __restrict__ an0,
    const float* __restrict__ aw1, const float* __restrict__ ab1,
    const float* __restrict__ ag1, const float* __restrict__ an1,
    const float* __restrict__ aw2, const float* __restrict__ ab2,
    const float* __restrict__ ag2, const float* __restrict__ an2,
    const float* __restrict__ mw0, const float* __restrict__ mb0,
    const float* __restrict__ mg0, const float* __restrict__ mn0,
    const float* __restrict__ mw1, const float* __restrict__ mb1,
    const float* __restrict__ mg1, const float* __restrict__ mn1,
    const float* __restrict__ mw2, const float* __restrict__ mb2,
    const float* __restrict__ mg2, const float* __restrict__ mn2,
    float* __restrict__ feats)
{
  __shared__ __align__(16) char smem[SMEM_BYTES];
  __bf16* Xs = (__bf16*)smem;
  __bf16* WT = (__bf16*)(smem + XBYTES);
  float*  Pp = (float*)(smem + XBYTES + 3 * WBYTES);
  const int tid = threadIdx.x;
  const int wid = tid >> 6;

  if (blockIdx.x < AGRID) {
    // ---- agent: 1 graph (49 nodes = 2 tiles) per block, cooperative ----
    const int bid = blockIdx.x;
    for (int i = tid; i < NA_ * 16; i += 256) {
      int n = i >> 4, k4 = (i & 15) * 4;
      float4 v = *(const float4*)&agent[((size_t)bid * NA_ + n) * 64 + k4];
      uint2 u; u.x = cvt_pk_bf16(v.x, v.y); u.y = cvt_pk_bf16(v.z, v.w);
      *(uint2*)&Xs[n * KP + k4] = u;
    }
    stage_wp(aw0, aw1, aw2, ab0, ag0, an0, ab1, ag1, an1, ab2, ag2, an2, smem);
    __syncthreads();

    if (wid < 2) tile_layer<4>(WT, Xs, wid * 32, wid ? 17 : 32,
                               Pp, Pp + 64, Pp + 128);
    __syncthreads();
    nmax_agent(smem);
    __syncthreads();
    if (wid < 2) tile_layer<8>(WT + 64 * KP, Xs, wid * 32, wid ? 17 : 32,
                               Pp + 192, Pp + 256, Pp + 320);
    __syncthreads();
    nmax_agent(smem);
    __syncthreads();
    if (wid < 2) tile_layer<8>(WT + 2 * 64 * KP, Xs, wid * 32, wid ? 17 : 32,
                               Pp + 384, Pp + 448, Pp + 512);
    __syncthreads();
    if (wid == 0) poly_store(Xs, 0, NA_, feats + (size_t)bid * 128);
  } else {
    // ---- map: 4 graphs per block, ONE graph per wave, barrier-free body ----
    const int mbid = blockIdx.x - AGRID;
    const int gbase = mbid * 4;
    for (int i = tid; i < 4 * NM_ * 16; i += 256) {
      int gg = i / (NM_ * 16);
      int rem = i - gg * (NM_ * 16);
      int n = rem >> 4, k4 = (rem & 15) * 4;
      float4 v = *(const float4*)&mapf[((size_t)(gbase + gg) * NM_ + n) * 64 + k4];
      uint2 u; u.x = cvt_pk_bf16(v.x, v.y); u.y = cvt_pk_bf16(v.z, v.w);
      *(uint2*)&Xs[(gg * 20 + n) * KP + k4] = u;
    }
    stage_wp(mw0, mw1, mw2, mb0, mg0, mn0, mb1, mg1, mn1, mb2, mg2, mn2, smem);
    __syncthreads();   // the only barrier on the map path

    const int wb = wid * 20;
    tile_layer<4>(WT, Xs, wb, NM_, Pp, Pp + 64, Pp + 128);
    nmax_wave(Xs, wb, NM_);
    tile_layer<8>(WT + 64 * KP, Xs, wb, NM_, Pp + 192, Pp + 256, Pp + 320);
    nmax_wave(Xs, wb, NM_);
    tile_layer<8>(WT + 2 * 64 * KP, Xs, wb, NM_, Pp + 384, Pp + 448, Pp + 512);
    poly_store(Xs, wb, NM_, feats + (size_t)(B_ + gbase + wid) * 128);
  }
}

// ---------------------------------------------------------------------------
// GAT (only destination node 0 is read) + readout MLP. One block per batch b.
// ---------------------------------------------------------------------------
__global__ __launch_bounds__(256) void gat_kernel(
    const float* __restrict__ feats,    // [129][B][128] fp32
    const float* __restrict__ fcw,      // [128][128]
    const float* __restrict__ attnw,    // [256]
    const float* __restrict__ mlpw,     // [128][60]
    const float* __restrict__ mlpb,     // [60]
    float* __restrict__ out)            // [B][60]
{
  const int b = blockIdx.x, tid = threadIdx.x;
  __shared__ float asrc[128], adst[128], was[128], wad[128];
  __shared__ float si[130];
  __shared__ float alpha[128], red[8], ubuf[128], hg[128];

  if (tid < 128) { asrc[tid] = attnw[tid]; adst[tid] = attnw[128 + tid]; }
  __syncthreads();

  if (tid < 128) {
    float s1 = 0.f, s2 = 0.f;
    for (int c = 0; c < 128; ++c) {
      float w = fcw[tid * 128 + c];
      s1 += w * asrc[c];
      s2 += w * adst[c];
    }
    was[tid] = s1; wad[tid] = s2;
  }
  __syncthreads();

  if (tid < 130) {
    const float* wa = (tid == 129) ? wad : was;
    int node = (tid == 129) ? 0 : tid;
    const float* fr = feats + ((size_t)node * B_ + b) * 128;
    float s = 0.f;
    for (int k = 0; k < 128; k += 4) {
      float4 f = *(const float4*)&fr[k];
      s += f.x * wa[k] + f.y * wa[k + 1] + f.z * wa[k + 2] + f.w * wa[k + 3];
    }
    si[tid] = s;
  }
  __syncthreads();

  float d0 = si[129];
  float e = -3.4e38f;
  if (tid < 128) {
    float x = si[tid + 1] + d0;
    e = (x > 0.f) ? x : 0.01f * x;
  }
  float m = e;
#pragma unroll
  for (int off = 32; off; off >>= 1) m = fmaxf(m, __shfl_xor(m, off));
  if ((tid & 63) == 0) red[tid >> 6] = m;
  __syncthreads();
  float mx = fmaxf(red[0], red[1]);
  float p = (tid < 128) ? expf(e - mx) : 0.f;
  float s = p;
#pragma unroll
  for (int off = 32; off; off >>= 1) s += __shfl_xor(s, off);
  if ((tid & 63) == 0) red[4 + (tid >> 6)] = s;
  __syncthreads();
  float denom = red[4] + red[5];
  if (tid < 128) alpha[tid] = p / denom;
  __syncthreads();

  if (tid < 128) {
    float u = 0.f;
    for (int t = 0; t < 128; ++t)
      u += alpha[t] * feats[((size_t)(t + 1) * B_ + b) * 128 + tid];
    ubuf[tid] = u;
  }
  __syncthreads();

  if (tid < 128) {
    float hh = 0.f;
    for (int k = 0; k < 128; ++k) hh += ubuf[k] * fcw[k * 128 + tid];
    hg[tid] = hh;
  }
  __syncthreads();

  if (tid < OUT_) {
    float o = mlpb[tid];
    for (int c = 0; c < 128; ++c) o += hg[c] * mlpw[c * OUT_ + tid];
    out[b * OUT_ + tid] = o;
  }
}

// ---------------------------------------------------------------------------
extern "C" void kernel_launch(void* const* d_in, const int* in_sizes, int n_in,
                              void* d_out, int out_size, void* d_ws, size_t ws_size,
                              hipStream_t stream) {
  (void)in_sizes; (void)n_in; (void)out_size; (void)ws_size;

  const float* agent = (const float*)d_in[0];   // [B][NA][64]
  const float* mapf  = (const float*)d_in[1];   // [P][B][NM][64]
  // d_in[2] = map_mask (all ones, unused)

  const float* aw0 = (const float*)d_in[3];
  const float* ab0 = (const float*)d_in[4];
  const float* ag0 = (const float*)d_in[5];
  const float* an0 = (const float*)d_in[6];
  const float* aw1 = (const float*)d_in[7];
  const float* ab1 = (const float*)d_in[8];
  const float* ag1 = (const float*)d_in[9];
  const float* an1 = (const float*)d_in[10];
  const float* aw2 = (const float*)d_in[11];
  const float* ab2 = (const float*)d_in[12];
  const float* ag2 = (const float*)d_in[13];
  const float* an2 = (const float*)d_in[14];

  const float* mw0 = (const float*)d_in[15];
  const float* mb0 = (const float*)d_in[16];
  const float* mg0 = (const float*)d_in[17];
  const float* mn0 = (const float*)d_in[18];
  const float* mw1 = (const float*)d_in[19];
  const float* mb1 = (const float*)d_in[20];
  const float* mg1 = (const float*)d_in[21];
  const float* mn1 = (const float*)d_in[22];
  const float* mw2 = (const float*)d_in[23];
  const float* mb2 = (const float*)d_in[24];
  const float* mg2 = (const float*)d_in[25];
  const float* mn2 = (const float*)d_in[26];

  const float* fcw   = (const float*)d_in[27];
  const float* attnw = (const float*)d_in[28];
  const float* mlpw  = (const float*)d_in[29];
  const float* mlpb  = (const float*)d_in[30];

  float* feats = (float*)d_ws;                 // [129][B][128] fp32 = 4.2 MB
  float* out = (float*)d_out;

  // fused agent(64 blocks) + map(2048 blocks); 1 graph per map wave
  subnet2<<<AGRID + MGRID, 256, 0, stream>>>(
      agent, mapf,
      aw0, ab0, ag0, an0, aw1, ab1, ag1, an1, aw2, ab2, ag2, an2,
      mw0, mb0, mg0, mn0, mw1, mb1, mg1, mn1, mw2, mb2, mg2, mn2,
      feats);

  // GAT column-0 + MLP readout
  gat_kernel<<<B_, 256, 0, stream>>>(feats, fcw, attnw, mlpw, mlpb, out);
}

// Round 8
// 59.832 us; speedup vs baseline: 4.4859x; 1.4011x over previous
//
#include <hip/hip_runtime.h>
#include <stdint.h>

// Problem dims (VectorNet): B=64, NA=49, NM=19, P=128, IN=64, H=64, OUT=60, H2=128
#define B_    64
#define NA_   49
#define NM_   19
#define P_    128
#define OUT_  60
#define AGRID 64          // agent: 1 graph/block (49 rows, 2 tiles)
#define MGRID 2048        // map: 4 graphs/block (76 rows, 3 tiles)
// X tile: 96 rows x 128 ch bf16, XOR-swizzled, row stride 256B
#define XR     96
#define XBYTES (XR * 256)            // 24576
#define PBYTES (9 * 64 * 4)          // 768 (3 layers x b/g/n x 64)
// W^T pack in d_ws after feats
#define FEATS_BYTES (129 * 64 * 128 * 4)     // 4227072
#define WT_UINTS_PER_SET 10240               // l0:2048, l1:4096, l2:4096

typedef __bf16 bf16x8 __attribute__((ext_vector_type(8)));
typedef float  f32x16 __attribute__((ext_vector_type(16)));
typedef unsigned short ushort_t;

__device__ __forceinline__ unsigned int cvt_pk_bf16(float lo, float hi) {
  unsigned int r;
  asm("v_cvt_pk_bf16_f32 %0, %1, %2" : "=v"(r) : "v"(lo), "v"(hi));
  return r;
}

__device__ __forceinline__ f32x16 zero16() {
  f32x16 z;
#pragma unroll
  for (int i = 0; i < 16; ++i) z[i] = 0.f;
  return z;
}

// swizzled X address: row stride 256B, byte ^= (row&7)<<4  (conflict-free
// for 32-row b128 column reads AND per-row u16 scans; preserves 16B align)
__device__ __forceinline__ int xswz(int row, int byteoff) {
  return row * 256 + (byteoff ^ ((row & 7) << 4));
}

// ---------------------------------------------------------------------------
// Prep: pack W^T (both subnets, 3 layers) as bf16 in A-fragment order:
//   uint index within set-layer = ((ks*2+mt)*64 + lr*2 + hi)*4 + j2
//   value = pack(W[k0*64+ch], W[(k0+1)*64+ch]),  k0=ks*16+hi*8+j2*2, ch=mt*32+lr
// grid 80 x 256 == 20480 uints exactly (set0=agent, set1=map)
// ---------------------------------------------------------------------------
__global__ void prep_wt(
    const float* __restrict__ aw0, const float* __restrict__ aw1,
    const float* __restrict__ aw2, const float* __restrict__ mw0,
    const float* __restrict__ mw1, const float* __restrict__ mw2,
    unsigned int* __restrict__ dst)
{
  const int U = blockIdx.x * 256 + threadIdx.x;
  const int set = U / WT_UINTS_PER_SET;
  const int u = U - set * WT_UINTS_PER_SET;
  int layer, ul;
  if (u < 2048)      { layer = 0; ul = u; }
  else if (u < 6144) { layer = 1; ul = u - 2048; }
  else               { layer = 2; ul = u - 6144; }
  const float* W;
  if (set == 0) W = (layer == 0) ? aw0 : (layer == 1 ? aw1 : aw2);
  else          W = (layer == 0) ? mw0 : (layer == 1 ? mw1 : mw2);
  int j2 = ul & 3, t = ul >> 2;
  int hi = t & 1; t >>= 1;
  int lr = t & 31; t >>= 5;
  int mt = t & 1;
  int ks = t >> 1;
  int k0 = ks * 16 + hi * 8 + j2 * 2;
  int ch = mt * 32 + lr;
  dst[U] = cvt_pk_bf16(W[k0 * 64 + ch], W[(k0 + 1) * 64 + ch]);
}

// ---------------------------------------------------------------------------
// One 32-row x 64-chan layer tile (verified r3/r5/r7 math):
//   v_mfma_f32_32x32x16_bf16, D = W^T (A) x^T (B)
//     A: row=lane&31 (chan), k=(lane>>5)*8+j ; B: col=lane&31 (graph-row)
//     D: col=lane&31 (row), chan=(reg&3)+8*(reg>>2)+4*(lane>>5)
//   A-fragments loaded from packed global W^T (L2-broadcast, coalesced).
//   LayerNorm(64) = in-lane adds + one shfl_xor(32). h written bf16, swizzled.
//   Lanes lr>=vr produce garbage (contained: D-col==B-row) and are write-guarded.
// ---------------------------------------------------------------------------
template<int KS>
__device__ __forceinline__ void tile_layer(
    const uint4* __restrict__ wt,   // packed W^T for this set+layer
    char* __restrict__ xs,          // LDS X base
    int xrow0, int vr,
    const float* __restrict__ Pb, const float* __restrict__ Pg,
    const float* __restrict__ Pn)
{
  const int lane = threadIdx.x & 63;
  const int lr   = lane & 31;
  const int hi   = lane >> 5;
  const int ch4  = hi * 4;

  bf16x8 afr[2][KS];
#pragma unroll
  for (int mt = 0; mt < 2; ++mt)
#pragma unroll
    for (int ks = 0; ks < KS; ++ks) {
      union { uint4 u; bf16x8 v; } c;
      c.u = wt[(ks * 2 + mt) * 64 + lr * 2 + hi];
      afr[mt][ks] = c.v;
    }

  const int br = xrow0 + lr;
  f32x16 acc0 = zero16(), acc1 = zero16();
#pragma unroll
  for (int ks = 0; ks < KS; ++ks) {
    bf16x8 bfr = *(const bf16x8*)(xs + xswz(br, ks * 32 + hi * 16));
    acc0 = __builtin_amdgcn_mfma_f32_32x32x16_bf16(afr[0][ks], bfr, acc0, 0, 0, 0);
    acc1 = __builtin_amdgcn_mfma_f32_32x32x16_bf16(afr[1][ks], bfr, acc1, 0, 0, 0);
  }

  // ---- bias + LayerNorm(64) fully in-register ----
  float v[2][16];
#pragma unroll
  for (int r = 0; r < 16; ++r) { v[0][r] = acc0[r]; v[1][r] = acc1[r]; }
#pragma unroll
  for (int mt = 0; mt < 2; ++mt)
#pragma unroll
    for (int b = 0; b < 4; ++b) {
      float4 tb = *(const float4*)&Pb[mt * 32 + 8 * b + ch4];
      v[mt][4*b+0] += tb.x; v[mt][4*b+1] += tb.y;
      v[mt][4*b+2] += tb.z; v[mt][4*b+3] += tb.w;
    }
  float s = 0.f, q = 0.f;
#pragma unroll
  for (int r = 0; r < 16; ++r) {
    s += v[0][r] + v[1][r];
    q = fmaf(v[0][r], v[0][r], q);
    q = fmaf(v[1][r], v[1][r], q);
  }
  s += __shfl_xor(s, 32);
  q += __shfl_xor(q, 32);
  float mu   = s * 0.015625f;
  float rstd = rsqrtf(fmaf(q, 0.015625f, -mu * mu) + 1e-5f);

#pragma unroll
  for (int mt = 0; mt < 2; ++mt)
#pragma unroll
    for (int b = 0; b < 4; ++b) {
      float4 tg = *(const float4*)&Pg[mt * 32 + 8 * b + ch4];
      float4 tn = *(const float4*)&Pn[mt * 32 + 8 * b + ch4];
      float h0 = fmaxf(0.f, fmaf((v[mt][4*b+0] - mu) * rstd, tg.x, tn.x));
      float h1 = fmaxf(0.f, fmaf((v[mt][4*b+1] - mu) * rstd, tg.y, tn.y));
      float h2 = fmaxf(0.f, fmaf((v[mt][4*b+2] - mu) * rstd, tg.z, tn.z));
      float h3 = fmaxf(0.f, fmaf((v[mt][4*b+3] - mu) * rstd, tg.w, tn.w));
      uint2 u; u.x = cvt_pk_bf16(h0, h1); u.y = cvt_pk_bf16(h2, h3);
      if (lr < vr)
        *(uint2*)(xs + xswz(br, mt * 64 + 16 * b + 8 * hi)) = u;
    }
}

// map neighbor-max: thread=(g=tid>>6, c=tid&63); graph g rows g*19..+18 packed.
// top-2 trick; h>=0 so bf16 bits compare as uint16. writes channel 64+c.
__device__ __forceinline__ void nmax_map(char* xs) {
  const int tid = threadIdx.x;
  const int g = tid >> 6, c = tid & 63;
  const int rb = g * NM_;
  unsigned int m1 = 0, m2 = 0;
  for (int n = 0; n < NM_; ++n) {
    unsigned int x = *(const ushort_t*)(xs + xswz(rb + n, 2 * c));
    if (x > m1) { m2 = m1; m1 = x; } else if (x > m2) m2 = x;
  }
  for (int n = 0; n < NM_; ++n) {
    unsigned int x = *(const ushort_t*)(xs + xswz(rb + n, 2 * c));
    *(ushort_t*)(xs + xswz(rb + n, 128 + 2 * c)) = (ushort_t)((x == m1) ? m2 : m1);
  }
}

// agent neighbor-max: all 4 waves scan all 49 nodes (redundant), split writes
__device__ __forceinline__ void nmax_agent(char* xs) {
  const int tid = threadIdx.x;
  const int c = tid & 63, wid = tid >> 6;
  unsigned int m1 = 0, m2 = 0;
  for (int n = 0; n < NA_; ++n) {
    unsigned int x = *(const ushort_t*)(xs + xswz(n, 2 * c));
    if (x > m1) { m2 = m1; m1 = x; } else if (x > m2) m2 = x;
  }
  int n0 = wid * 13, n1 = (n0 + 13 > NA_) ? NA_ : n0 + 13;
  for (int n = n0; n < n1; ++n) {
    unsigned int x = *(const ushort_t*)(xs + xswz(n, 2 * c));
    *(ushort_t*)(xs + xswz(n, 128 + 2 * c)) = (ushort_t)((x == m1) ? m2 : m1);
  }
}

// stage 3 layers of bias/gamma/beta into LDS (768B)
__device__ __forceinline__ void stage_params(
    const float* b0, const float* g0, const float* n0,
    const float* b1, const float* g1, const float* n1,
    const float* b2, const float* g2, const float* n2, float* Pp)
{
  const int tid = threadIdx.x;
  if (tid < 64) {
    Pp[      tid] = b0[tid]; Pp[ 64 + tid] = g0[tid]; Pp[128 + tid] = n0[tid];
    Pp[192 + tid] = b1[tid]; Pp[256 + tid] = g1[tid]; Pp[320 + tid] = n1[tid];
    Pp[384 + tid] = b2[tid]; Pp[448 + tid] = g2[tid]; Pp[512 + tid] = n2[tid];
  }
}

// ---------------------------------------------------------------------------
__global__ __launch_bounds__(256, 4) void subnet3(
    const float* __restrict__ agent, const float* __restrict__ mapf,
    const float* __restrict__ ab0, const float* __restrict__ ag0,
    const float* __restrict__ an0, const float* __restrict__ ab1,
    const float* __restrict__ ag1, const float* __restrict__ an1,
    const float* __restrict__ ab2, const float* __restrict__ ag2,
    const float* __restrict__ an2, const float* __restrict__ mb0,
    const float* __restrict__ mg0, const float* __restrict__ mn0,
    const float* __restrict__ mb1, const float* __restrict__ mg1,
    const float* __restrict__ mn1, const float* __restrict__ mb2,
    const float* __restrict__ mg2, const float* __restrict__ mn2,
    const uint4* __restrict__ wt,   // packed W^T (set0 agent, set1 map)
    float* __restrict__ feats)
{
  __shared__ __align__(16) char smem[XBYTES + PBYTES];
  char*  xs = smem;
  float* Pp = (float*)(smem + XBYTES);
  const int tid = threadIdx.x;
  const int wid = tid >> 6;

  if (blockIdx.x < AGRID) {
    // ---- agent: 1 graph (49 rows, 2 tiles: valid 32,17) per block ----
    const int bid = blockIdx.x;
    for (int i = tid; i < NA_ * 16; i += 256) {
      int row = i >> 4, k4 = (i & 15) * 4;
      float4 v = *(const float4*)&agent[((size_t)bid * NA_ + row) * 64 + k4];
      uint2 u; u.x = cvt_pk_bf16(v.x, v.y); u.y = cvt_pk_bf16(v.z, v.w);
      *(uint2*)(xs + xswz(row, 8 * (i & 15))) = u;
    }
    stage_params(ab0, ag0, an0, ab1, ag1, an1, ab2, ag2, an2, Pp);
    __syncthreads();
    if (wid < 2) tile_layer<4>(wt, xs, wid * 32, wid ? 17 : 32,
                               Pp, Pp + 64, Pp + 128);
    __syncthreads();
    nmax_agent(xs);
    __syncthreads();
    if (wid < 2) tile_layer<8>(wt + 512, xs, wid * 32, wid ? 17 : 32,
                               Pp + 192, Pp + 256, Pp + 320);
    __syncthreads();
    nmax_agent(xs);
    __syncthreads();
    if (wid < 2) tile_layer<8>(wt + 1536, xs, wid * 32, wid ? 17 : 32,
                               Pp + 384, Pp + 448, Pp + 512);
    __syncthreads();
    if (tid < 64) {   // poly: both halves = max over nodes (N>=2)
      unsigned int m1 = 0;
      for (int n = 0; n < NA_; ++n) {
        unsigned int x = *(const ushort_t*)(xs + xswz(n, 2 * tid));
        m1 = x > m1 ? x : m1;
      }
      float f = __uint_as_float(m1 << 16);
      feats[(size_t)bid * 128 + tid] = f;
      feats[(size_t)bid * 128 + 64 + tid] = f;
    }
  } else {
    // ---- map: 4 graphs packed (76 rows, 3 tiles: valid 32,32,12) ----
    const uint4* wtm = wt + 2560;   // set 1
    const int mbid = blockIdx.x - AGRID;
    const int gbase = mbid * 4;
    for (int i = tid; i < 76 * 16; i += 256) {
      int row = i >> 4, k4 = (i & 15) * 4;
      float4 v = *(const float4*)&mapf[((size_t)gbase * NM_ + row) * 64 + k4];
      uint2 u; u.x = cvt_pk_bf16(v.x, v.y); u.y = cvt_pk_bf16(v.z, v.w);
      *(uint2*)(xs + xswz(row, 8 * (i & 15))) = u;
    }
    stage_params(mb0, mg0, mn0, mb1, mg1, mn1, mb2, mg2, mn2, Pp);
    __syncthreads();
    if (wid < 3) tile_layer<4>(wtm, xs, wid * 32, (wid == 2) ? 12 : 32,
                               Pp, Pp + 64, Pp + 128);
    __syncthreads();
    nmax_map(xs);
    __syncthreads();
    if (wid < 3) tile_layer<8>(wtm + 512, xs, wid * 32, (wid == 2) ? 12 : 32,
                               Pp + 192, Pp + 256, Pp + 320);
    __syncthreads();
    nmax_map(xs);
    __syncthreads();
    if (wid < 3) tile_layer<8>(wtm + 1536, xs, wid * 32, (wid == 2) ? 12 : 32,
                               Pp + 384, Pp + 448, Pp + 512);
    __syncthreads();
    {   // poly per (g,c)
      const int g = tid >> 6, c = tid & 63;
      const int rb = g * NM_;
      unsigned int m1 = 0;
      for (int n = 0; n < NM_; ++n) {
        unsigned int x = *(const ushort_t*)(xs + xswz(rb + n, 2 * c));
        m1 = x > m1 ? x : m1;
      }
      float f = __uint_as_float(m1 << 16);
      size_t slot = (size_t)(B_ + gbase + g);
      feats[slot * 128 + c] = f;
      feats[slot * 128 + 64 + c] = f;
    }
  }
}

// ---------------------------------------------------------------------------
// GAT (only destination node 0 is read) + readout MLP. One block per batch b.
// ---------------------------------------------------------------------------
__global__ __launch_bounds__(256) void gat_kernel(
    const float* __restrict__ feats,    // [129][B][128] fp32
    const float* __restrict__ fcw,      // [128][128]
    const float* __restrict__ attnw,    // [256]
    const float* __restrict__ mlpw,     // [128][60]
    const float* __restrict__ mlpb,     // [60]
    float* __restrict__ out)            // [B][60]
{
  const int b = blockIdx.x, tid = threadIdx.x;
  __shared__ float asrc[128], adst[128], was[128], wad[128];
  __shared__ float si[130];
  __shared__ float alpha[128], red[8], ubuf[128], hg[128];

  if (tid < 128) { asrc[tid] = attnw[tid]; adst[tid] = attnw[128 + tid]; }
  __syncthreads();

  if (tid < 128) {
    float s1 = 0.f, s2 = 0.f;
    for (int c = 0; c < 128; ++c) {
      float w = fcw[tid * 128 + c];
      s1 += w * asrc[c];
      s2 += w * adst[c];
    }
    was[tid] = s1; wad[tid] = s2;
  }
  __syncthreads();

  if (tid < 130) {
    const float* wa = (tid == 129) ? wad : was;
    int node = (tid == 129) ? 0 : tid;
    const float* fr = feats + ((size_t)node * B_ + b) * 128;
    float s = 0.f;
    for (int k = 0; k < 128; k += 4) {
      float4 f = *(const float4*)&fr[k];
      s += f.x * wa[k] + f.y * wa[k + 1] + f.z * wa[k + 2] + f.w * wa[k + 3];
    }
    si[tid] = s;
  }
  __syncthreads();

  float d0 = si[129];
  float e = -3.4e38f;
  if (tid < 128) {
    float x = si[tid + 1] + d0;
    e = (x > 0.f) ? x : 0.01f * x;
  }
  float m = e;
#pragma unroll
  for (int off = 32; off; off >>= 1) m = fmaxf(m, __shfl_xor(m, off));
  if ((tid & 63) == 0) red[tid >> 6] = m;
  __syncthreads();
  float mx = fmaxf(red[0], red[1]);
  float p = (tid < 128) ? expf(e - mx) : 0.f;
  float s = p;
#pragma unroll
  for (int off = 32; off; off >>= 1) s += __shfl_xor(s, off);
  if ((tid & 63) == 0) red[4 + (tid >> 6)] = s;
  __syncthreads();
  float denom = red[4] + red[5];
  if (tid < 128) alpha[tid] = p / denom;
  __syncthreads();

  if (tid < 128) {
    float u = 0.f;
    for (int t = 0; t < 128; ++t)
      u += alpha[t] * feats[((size_t)(t + 1) * B_ + b) * 128 + tid];
    ubuf[tid] = u;
  }
  __syncthreads();

  if (tid < 128) {
    float hh = 0.f;
    for (int k = 0; k < 128; ++k) hh += ubuf[k] * fcw[k * 128 + tid];
    hg[tid] = hh;
  }
  __syncthreads();

  if (tid < OUT_) {
    float o = mlpb[tid];
    for (int c = 0; c < 128; ++c) o += hg[c] * mlpw[c * OUT_ + tid];
    out[b * OUT_ + tid] = o;
  }
}

// ---------------------------------------------------------------------------
extern "C" void kernel_launch(void* const* d_in, const int* in_sizes, int n_in,
                              void* d_out, int out_size, void* d_ws, size_t ws_size,
                              hipStream_t stream) {
  (void)in_sizes; (void)n_in; (void)out_size; (void)ws_size;

  const float* agent = (const float*)d_in[0];   // [B][NA][64]
  const float* mapf  = (const float*)d_in[1];   // [P][B][NM][64]
  // d_in[2] = map_mask (all ones, unused)

  const float* aw0 = (const float*)d_in[3];
  const float* ab0 = (const float*)d_in[4];
  const float* ag0 = (const float*)d_in[5];
  const float* an0 = (const float*)d_in[6];
  const float* aw1 = (const float*)d_in[7];
  const float* ab1 = (const float*)d_in[8];
  const float* ag1 = (const float*)d_in[9];
  const float* an1 = (const float*)d_in[10];
  const float* aw2 = (const float*)d_in[11];
  const float* ab2 = (const float*)d_in[12];
  const float* ag2 = (const float*)d_in[13];
  const float* an2 = (const float*)d_in[14];

  const float* mw0 = (const float*)d_in[15];
  const float* mb0 = (const float*)d_in[16];
  const float* mg0 = (const float*)d_in[17];
  const float* mn0 = (const float*)d_in[18];
  const float* mw1 = (const float*)d_in[19];
  const float* mb1 = (const float*)d_in[20];
  const float* mg1 = (const float*)d_in[21];
  const float* mn1 = (const float*)d_in[22];
  const float* mw2 = (const float*)d_in[23];
  const float* mb2 = (const float*)d_in[24];
  const float* mg2 = (const float*)d_in[25];
  const float* mn2 = (const float*)d_in[26];

  const float* fcw   = (const float*)d_in[27];
  const float* attnw = (const float*)d_in[28];
  const float* mlpw  = (const float*)d_in[29];
  const float* mlpb  = (const float*)d_in[30];

  float* feats = (float*)d_ws;                         // 4.23 MB
  unsigned int* wt = (unsigned int*)((char*)d_ws + FEATS_BYTES);  // 80 KB
  float* out = (float*)d_out;

  // 1) pack W^T bf16 in A-fragment order (L2-resident for all subnet blocks)
  prep_wt<<<80, 256, 0, stream>>>(aw0, aw1, aw2, mw0, mw1, mw2, wt);

  // 2) fused agent(64) + map(2048) subnet; 4 blocks/CU, dense row packing
  subnet3<<<AGRID + MGRID, 256, 0, stream>>>(
      agent, mapf,
      ab0, ag0, an0, ab1, ag1, an1, ab2, ag2, an2,
      mb0, mg0, mn0, mb1, mg1, mn1, mb2, mg2, mn2,
      (const uint4*)wt, feats);

  // 3) GAT column-0 + MLP readout
  gat_kernel<<<B_, 256, 0, stream>>>(feats, fcw, attnw, mlpw, mlpb, out);
}